// Round 11
// baseline (321.495 us; speedup 1.0000x reference)
//
#include <hip/hip_runtime.h>
#include <hip/hip_bf16.h>

#define T_SEQ 2048
#define DMODEL 4096
#define NH 32
#define NKV 8
#define HD 128
#define RVIRT 128
#define TKV (RVIRT + T_SEQ)   // 2176

typedef __attribute__((ext_vector_type(8))) short s16x8;
typedef __attribute__((ext_vector_type(4))) short s16x4;
typedef __attribute__((ext_vector_type(4))) float f32x4;
typedef __attribute__((ext_vector_type(4))) float float4v;

static __device__ __forceinline__ short f2bf(float f) {
  union { __hip_bfloat16 h; short s; } u; u.h = __float2bfloat16(f); return u.s;
}

static __device__ __forceinline__ void gload16(const void* g, void* l) {
  __builtin_amdgcn_global_load_lds(
      (const __attribute__((address_space(1))) void*)g,
      (__attribute__((address_space(3))) void*)l, 16, 0, 0);
}

#define TOPSYNC() \
  __builtin_amdgcn_s_barrier(); \
  asm volatile("s_waitcnt lgkmcnt(0)" ::: "memory"); \
  __builtin_amdgcn_sched_barrier(0);

// ---------------------------------------------------------------------------
// prep_kernel: fused {convert_x | transpose Wq | transpose Wk | transpose Wv}.
// ---------------------------------------------------------------------------
__global__ __launch_bounds__(256) void prep_kernel(const float* __restrict__ hidden,
    short* __restrict__ Xb, const float* __restrict__ Wq,
    const float* __restrict__ Wk, const float* __restrict__ Wv,
    short* __restrict__ Wall)
{
  const int bid = blockIdx.x, tid = threadIdx.x;
  if (bid < 4096) {
    int i = (bid * 256 + tid) * 8;
    float4v a = *(const float4v*)(hidden + i);
    float4v b = *(const float4v*)(hidden + i + 4);
    s16x8 o;
#pragma unroll
    for (int j = 0; j < 4; ++j) { o[j] = f2bf(a[j]); o[4 + j] = f2bf(b[j]); }
    *(s16x8*)(Xb + i) = o;
    return;
  }
  // transpose+convert branch
  __shared__ float tile[64][65];
  const float* src; short* dst; int N, k0, n0;
  if (bid < 8192) {
    int b = bid - 4096; src = Wq; dst = Wall; N = 4096;
    n0 = (b & 63) * 64; k0 = (b >> 6) * 64;
  } else if (bid < 9216) {
    int b = bid - 8192; src = Wk; dst = Wall + (size_t)4096 * DMODEL; N = 1024;
    n0 = (b & 15) * 64; k0 = (b >> 4) * 64;
  } else {
    int b = bid - 9216; src = Wv; dst = Wall + (size_t)5120 * DMODEL; N = 1024;
    n0 = (b & 15) * 64; k0 = (b >> 4) * 64;
  }
  const int K = DMODEL;
  const int rr = tid >> 4, c4 = (tid & 15) * 4;
#pragma unroll
  for (int it = 0; it < 4; ++it) {
    int row = it * 16 + rr;
    float4v v = *(const float4v*)(src + (size_t)(k0 + row) * N + n0 + c4);
    tile[row][c4] = v[0]; tile[row][c4 + 1] = v[1];
    tile[row][c4 + 2] = v[2]; tile[row][c4 + 3] = v[3];
  }
  __syncthreads();
  const int n = tid >> 3, seg = tid & 7;
#pragma unroll
  for (int it = 0; it < 2; ++it) {
    int nn = it * 32 + n;
    s16x8 o;
#pragma unroll
    for (int j = 0; j < 8; ++j) o[j] = f2bf(tile[seg * 8 + j][nn]);
    *(s16x8*)(dst + (size_t)(n0 + nn) * K + k0 + seg * 8) = o;
  }
}

// ---------------------------------------------------------------------------
// gemm_qkv: 256x192 tile, 8 waves (4M x 2N), BK=64, 3 phases/K-tile.
// Grid 8x32 = 256 blocks = 100% CU fill.
// r11 change (slack-max staging): ALL ph0-consumed units {A0..A3,B0}(t+1)
// issued at ph0(t) -> every unit now has 3 phases (~900cy) issue-to-consume
// slack (was 2 for A3,B0,B1). Waits re-derived: ph0-end vmcnt(6) [drain
// B1(t)], ph1-end vmcnt(6) [drain B2(t)], ph2-end vmcnt(2) [drain
// A*,B0(t+1), keep B1,B2(t+1) flying]. Never drains a load younger than
// 3 phases. Tail: 1/0/none. Prologue: stage 7, vmcnt(2).
// Cv (V^T) output stored PRE-SWIZZLED for attn's global_load_lds staging.
// ---------------------------------------------------------------------------
__global__ __launch_bounds__(512, 2) void gemm_qkv(const short* __restrict__ Ab,
    const short* __restrict__ Btb, float* __restrict__ C0,
    float* __restrict__ Ck, short* __restrict__ Cv, int K)
{
  constexpr int SLOT = 57344;           // 32KB A + 24KB B
  __shared__ __align__(16) char lds[2 * SLOT];
  const int tid = threadIdx.x, lane = tid & 63, w = tid >> 6;
  const int lo = lane & 15, g = lane >> 4;
  const int wm = w >> 1, wn = w & 1;    // 4M x 2N
  const int m0 = blockIdx.y * 256, n0 = blockIdx.x * 192;
  const int NT = K >> 6;
  const int aswz = (lo & 7) << 4;
  const int t8 = tid >> 3, t7 = tid & 7;
  const int swc = (t7 ^ (t8 & 7)) * 8;  // shorts, pre-swizzled col

  const short* As = Ab + (size_t)(m0 + t8) * K + swc;
  const short* Bs[3];
#pragma unroll
  for (int jj = 0; jj < 3; ++jj) {
    int row = (t8 >> 5) * 96 + (2 * jj + ((t8 >> 4) & 1)) * 16 + (t8 & 15);
    Bs[jj] = Btb + (size_t)(n0 + row) * K + swc;
  }
  auto SA = [&](char* nb, int jj, int y) {
    gload16(As + (size_t)jj * 64 * K + y * 64, nb + tid * 16 + jj * 8192);
  };
  auto SB = [&](char* nb, int jj, int y) {
    gload16(Bs[jj] + y * 64, nb + 32768 + tid * 16 + jj * 8192);
  };

  f32x4 acc[4][6];
#pragma unroll
  for (int i = 0; i < 4; ++i)
#pragma unroll
    for (int j = 0; j < 6; ++j) acc[i][j] = (f32x4){0.f, 0.f, 0.f, 0.f};

  s16x8 a[4][2], bq[2][2];

#define QLDB(P) \
  _Pragma("unroll") for (int jj = 0; jj < 2; ++jj) \
  _Pragma("unroll") for (int kk = 0; kk < 2; ++kk) \
    bq[jj][kk] = *(const s16x8*)(bu + 32768 + ((P) * 64 + wn * 32 + jj * 16 + lo) * 128 + ((kk * 64 + g * 16) ^ aswz));
#define QMMQ(P) \
  __builtin_amdgcn_s_setprio(1); \
  _Pragma("unroll") for (int i = 0; i < 4; ++i) \
  _Pragma("unroll") for (int jj = 0; jj < 2; ++jj) { \
    f32x4 z = __builtin_amdgcn_mfma_f32_16x16x32_bf16(a[i][0], bq[jj][0], acc[i][(P) * 2 + jj], 0, 0, 0); \
    acc[i][(P) * 2 + jj] = __builtin_amdgcn_mfma_f32_16x16x32_bf16(a[i][1], bq[jj][1], z, 0, 0, 0); \
  } \
  __builtin_amdgcn_s_setprio(0);

  // prologue: tile 0 fully staged; keep B1,B2 (youngest 2) in flight
  SA(lds, 0, 0); SA(lds, 1, 0); SA(lds, 2, 0); SA(lds, 3, 0);
  SB(lds, 0, 0); SB(lds, 1, 0); SB(lds, 2, 0);
  asm volatile("s_waitcnt vmcnt(2)" ::: "memory");
  __builtin_amdgcn_s_barrier();

  for (int t = 0; t < NT; ++t) {
    const char* bu = lds + (t & 1) * SLOT;
    char* nb = lds + ((t + 1) & 1) * SLOT;
    const bool pre = (t + 1 < NT);
    // ---- ph0: cols 0,1 -- issue ALL next-tile ph0-consumed units here
#pragma unroll
    for (int i = 0; i < 4; ++i)
#pragma unroll
      for (int kk = 0; kk < 2; ++kk)
        a[i][kk] = *(const s16x8*)(bu + (wm * 64 + i * 16 + lo) * 128 + ((kk * 64 + g * 16) ^ aswz));
    QLDB(0);
    if (pre) { SA(nb, 0, t + 1); SA(nb, 1, t + 1); SA(nb, 2, t + 1); SA(nb, 3, t + 1); SB(nb, 0, t + 1); }
    TOPSYNC();
    QMMQ(0);
    if (pre) asm volatile("s_waitcnt vmcnt(6)" ::: "memory");   // drain B1(t)
    else     asm volatile("s_waitcnt vmcnt(1)" ::: "memory");
    __builtin_amdgcn_s_barrier();
    // ---- ph1: cols 2,3
    QLDB(1);
    if (pre) SB(nb, 1, t + 1);
    TOPSYNC();
    QMMQ(1);
    if (pre) asm volatile("s_waitcnt vmcnt(6)" ::: "memory");   // drain B2(t)
    else     asm volatile("s_waitcnt vmcnt(0)" ::: "memory");
    __builtin_amdgcn_s_barrier();
    // ---- ph2: cols 4,5
    QLDB(2);
    if (pre) SB(nb, 2, t + 1);
    TOPSYNC();
    QMMQ(2);
    if (pre) asm volatile("s_waitcnt vmcnt(2)" ::: "memory");   // drain A*,B0(t+1)
    __builtin_amdgcn_s_barrier();
  }
#undef QLDB
#undef QMMQ

#pragma unroll
  for (int i = 0; i < 4; ++i)
#pragma unroll
    for (int j = 0; j < 6; ++j)
#pragma unroll
      for (int r = 0; r < 4; ++r) {
        int row = m0 + wm * 64 + i * 16 + g * 4 + r;
        int col = n0 + wn * 96 + j * 16 + lo;
        float val = acc[i][j][r];
        if (col < 4096) C0[(size_t)row * 4096 + col] = val;
        else if (col < 5120) Ck[(size_t)row * 1024 + (col - 4096)] = val;
        else {
          int vcol = col - 5120;
          int d = vcol & 127;
          int rp = (RVIRT + row) ^ ((((d >> 3) ^ d) & 7) << 3);
          Cv[((size_t)(vcol >> 7) * HD + d) * TKV + rp] = f2bf(val);
        }
      }
}

// ---------------------------------------------------------------------------
// gemm_out: 128x256 tile, 8 waves (2M x 4N), BK=64, 2 phases/K-tile.
// Grid 16x16 = 256 blocks = 100% fill.
// r11 change: all 6 units of t+1 issued at ph0(t) (B2/B3 slack 2->3 phases).
// Waits: ph0-end vmcnt(6) [drain B2,B3(t)], ph1-end vmcnt(2) [drain
// A0,A1,B0,B1(t+1)]. Tail: 0/none. Prologue: stage 6, vmcnt(2).
// ---------------------------------------------------------------------------
__global__ __launch_bounds__(512, 2) void gemm_out(const short* __restrict__ Ab,
    const short* __restrict__ Btb, float* __restrict__ C0, int K)
{
  constexpr int SLOT = 49152;           // 16KB A + 32KB B
  __shared__ __align__(16) char lds[2 * SLOT];
  const int tid = threadIdx.x, lane = tid & 63, w = tid >> 6;
  const int lo = lane & 15, g = lane >> 4;
  const int wm = w >> 2, wn = w & 3;    // 2M x 4N
  const int m0 = blockIdx.y * 128, n0 = blockIdx.x * 256;
  const int NT = K >> 6;
  const int aswz = (lo & 7) << 4;
  const int t8 = tid >> 3, t7 = tid & 7;
  const int swc = (t7 ^ (t8 & 7)) * 8;  // shorts

  const short* As = Ab + (size_t)(m0 + t8) * K + swc;
  const short* Bs[4];
#pragma unroll
  for (int jj = 0; jj < 4; ++jj) {
    int row = (t8 >> 4) * 64 + jj * 16 + (t8 & 15);
    Bs[jj] = Btb + (size_t)(n0 + row) * K + swc;
  }
  auto SA = [&](char* nb, int jj, int y) {
    gload16(As + (size_t)jj * 64 * K + y * 64, nb + tid * 16 + jj * 8192);
  };
  auto SB = [&](char* nb, int jj, int y) {
    gload16(Bs[jj] + y * 64, nb + 16384 + tid * 16 + jj * 8192);
  };

  f32x4 acc[4][4];
#pragma unroll
  for (int i = 0; i < 4; ++i)
#pragma unroll
    for (int j = 0; j < 4; ++j) acc[i][j] = (f32x4){0.f, 0.f, 0.f, 0.f};

  s16x8 a[4][2], bq[2][2];

#define OLDB(P) \
  _Pragma("unroll") for (int jj = 0; jj < 2; ++jj) \
  _Pragma("unroll") for (int kk = 0; kk < 2; ++kk) \
    bq[jj][kk] = *(const s16x8*)(bu + 16384 + (((P) * 2 + jj) * 64 + wn * 16 + lo) * 128 + ((kk * 64 + g * 16) ^ aswz));
#define OMMQ(P) \
  __builtin_amdgcn_s_setprio(1); \
  _Pragma("unroll") for (int i = 0; i < 4; ++i) \
  _Pragma("unroll") for (int jj = 0; jj < 2; ++jj) { \
    f32x4 z = __builtin_amdgcn_mfma_f32_16x16x32_bf16(a[i][0], bq[jj][0], acc[i][(P) * 2 + jj], 0, 0, 0); \
    acc[i][(P) * 2 + jj] = __builtin_amdgcn_mfma_f32_16x16x32_bf16(a[i][1], bq[jj][1], z, 0, 0, 0); \
  } \
  __builtin_amdgcn_s_setprio(0);

  SA(lds, 0, 0); SA(lds, 1, 0);
  SB(lds, 0, 0); SB(lds, 1, 0); SB(lds, 2, 0); SB(lds, 3, 0);
  asm volatile("s_waitcnt vmcnt(2)" ::: "memory");
  __builtin_amdgcn_s_barrier();

  for (int t = 0; t < NT; ++t) {
    const char* bu = lds + (t & 1) * SLOT;
    char* nb = lds + ((t + 1) & 1) * SLOT;
    const bool pre = (t + 1 < NT);
    // ---- ph0: cols 0,1 -- issue ALL of t+1's units here
#pragma unroll
    for (int i = 0; i < 4; ++i)
#pragma unroll
      for (int kk = 0; kk < 2; ++kk)
        a[i][kk] = *(const s16x8*)(bu + (wm * 64 + i * 16 + lo) * 128 + ((kk * 64 + g * 16) ^ aswz));
    OLDB(0);
    if (pre) { SA(nb, 0, t + 1); SA(nb, 1, t + 1);
               SB(nb, 0, t + 1); SB(nb, 1, t + 1); SB(nb, 2, t + 1); SB(nb, 3, t + 1); }
    TOPSYNC();
    OMMQ(0);
    if (pre) asm volatile("s_waitcnt vmcnt(6)" ::: "memory");   // drain B2,B3(t)
    else     asm volatile("s_waitcnt vmcnt(0)" ::: "memory");
    __builtin_amdgcn_s_barrier();
    // ---- ph1: cols 2,3
    OLDB(1);
    TOPSYNC();
    OMMQ(1);
    if (pre) asm volatile("s_waitcnt vmcnt(2)" ::: "memory");   // drain A*,B0,B1(t+1)
    __builtin_amdgcn_s_barrier();
  }
#undef OLDB
#undef OMMQ

#pragma unroll
  for (int i = 0; i < 4; ++i)
#pragma unroll
    for (int j = 0; j < 4; ++j)
#pragma unroll
      for (int r = 0; r < 4; ++r) {
        int row = m0 + wm * 64 + i * 16 + g * 4 + r;
        int col = n0 + wn * 64 + j * 16 + lo;
        C0[(size_t)row * 4096 + col] = acc[i][j][r];
      }
}

// ---------------------------------------------------------------------------
// ropeinj_kernel: fused {rope Q | rope K | virtual-KV inject}.
// ---------------------------------------------------------------------------
__global__ __launch_bounds__(256) void ropeinj_kernel(
    const float* __restrict__ q_projf, const float* __restrict__ k_projf,
    const float* __restrict__ qnw, const float* __restrict__ knw,
    const float* __restrict__ cosT, const float* __restrict__ sinT,
    const float* __restrict__ vk, const float* __restrict__ vv,
    const float* __restrict__ logit,
    short* __restrict__ Qr, short* __restrict__ Kr, short* __restrict__ Vt,
    float qscale)
{
  const int bid = blockIdx.x, tid = threadIdx.x;
  if (bid < 20480) {
    const float* proj; const float* nw; short* outp;
    int nh_shift, rows_total, row0, kswz; float qs; int wid;
    if (bid < 16384) {
      proj = q_projf; nw = qnw; outp = Qr; nh_shift = 5;
      rows_total = T_SEQ; row0 = 0; qs = qscale; kswz = 0;
      wid = bid * 4 + (tid >> 6);
    } else {
      proj = k_projf; nw = knw; outp = Kr; nh_shift = 3;
      rows_total = TKV; row0 = RVIRT; qs = 1.0f; kswz = 1;
      wid = (bid - 16384) * 4 + (tid >> 6);
    }
    int lane = tid & 63;
    int nh = 1 << nh_shift;
    int t = wid >> nh_shift;
    int hh = wid & (nh - 1);
    const float* src = proj + (size_t)t * (nh * HD) + hh * HD;
    float x1 = src[lane];
    float x2 = src[lane + 64];
    float ss = x1 * x1 + x2 * x2;
#pragma unroll
    for (int off = 32; off > 0; off >>= 1) ss += __shfl_xor(ss, off, 64);
    float rms = rsqrtf(ss * (1.0f / 128.0f) + 1e-6f);
    float n1 = x1 * rms * nw[lane];
    float n2 = x2 * rms * nw[lane + 64];
    float c1 = cosT[t * HD + lane], c2 = cosT[t * HD + lane + 64];
    float s1 = sinT[t * HD + lane], s2 = sinT[t * HD + lane + 64];
    short* dst = outp + ((size_t)hh * rows_total + row0 + t) * HD;
    int sw = kswz ? (((row0 + t) & 7) << 3) : 0;
    dst[lane ^ sw]        = f2bf((n1 * c1 - n2 * s1) * qs);
    dst[(lane + 64) ^ sw] = f2bf((n2 * c2 + n1 * s2) * qs);
  } else {
    int idx = (bid - 20480) * 256 + tid;   // < 8*128*128
    float alpha = 0.5f / (1.0f + __expf(-logit[0]));
    int kv = idx >> 14, rem = idx & 16383, r = rem >> 7, d = rem & 127;
    int swk = (r & 7) << 3;
    Kr[((size_t)kv * TKV + r) * HD + (d ^ swk)] = f2bf(vk[idx] * alpha);
    int swv = ((d ^ (d >> 3)) & 7) << 3;
    Vt[((size_t)kv * HD + d) * TKV + (r ^ swv)] = f2bf(vv[idx] * alpha);
  }
}

// ---------------------------------------------------------------------------
// attn_wo_kernel: fused {flash attention v6 | transpose Wo}.  (frozen, r10)
// ---------------------------------------------------------------------------
__global__ __launch_bounds__(256, 2) void attn_wo_kernel(const short* __restrict__ Qr,
    const short* __restrict__ Kr, const short* __restrict__ Vt,
    short* __restrict__ out, const float* __restrict__ Wo,
    short* __restrict__ Wot)
{
  __shared__ __align__(16) char smem[81920];
  const int tid = threadIdx.x;
  const int bid = blockIdx.x;

  if (bid >= 512) {
    // ---------------- Wo transpose branch ----------------
    float* tile = (float*)smem;               // [64][65]
    int b = bid - 512;
    const int n0 = (b & 63) * 64, k0 = (b >> 6) * 64;
    const int N = 4096, K = 4096;
    const int rr = tid >> 4, c4 = (tid & 15) * 4;
#pragma unroll
    for (int it = 0; it < 4; ++it) {
      int row = it * 16 + rr;
      float4v v = *(const float4v*)(Wo + (size_t)(k0 + row) * N + n0 + c4);
      tile[row * 65 + c4] = v[0]; tile[row * 65 + c4 + 1] = v[1];
      tile[row * 65 + c4 + 2] = v[2]; tile[row * 65 + c4 + 3] = v[3];
    }
    __syncthreads();
    const int n = tid >> 3, seg = tid & 7;
#pragma unroll
    for (int it = 0; it < 2; ++it) {
      int nn = it * 32 + n;
      s16x8 o;
#pragma unroll
      for (int j = 0; j < 8; ++j) o[j] = f2bf(tile[(seg * 8 + j) * 65 + nn]);
      *(s16x8*)(Wot + (size_t)(n0 + nn) * K + k0 + seg * 8) = o;
    }
    return;
  }

  // ---------------- attention v6 branch ----------------
  short* Ks0 = (short*)smem;                  // [2][64*128]
  short* Vs0 = (short*)(smem + 32768);        // [2][128*64]
  char*  Ps  = smem + 65536;                  // per wave: 2KB A + 2KB B
  const int lane = tid & 63, w = tid >> 6;
  const int kvh = bid & 7;                    // XCD-aligned kv-head
  const int r5 = bid >> 3;
  const int h = kvh * 4 + (r5 & 3);
  const int bx = r5 >> 2;                     // 0..15
  const int lo = lane & 15, g = lane >> 4;
  const int q0A = bx * 64, q0B = (31 - bx) * 64;
  const int ntA = bx + 3, ntB = 34 - bx;
  char* PsA = Ps + w * 4096;
  char* PsB = PsA + 2048;
  const short* Kb = Kr + (size_t)kvh * TKV * HD;
  const short* Vb = Vt + (size_t)kvh * HD * TKV;

  s16x8 qfA[4], qfB[4];
#pragma unroll
  for (int kk = 0; kk < 4; ++kk) {
    qfA[kk] = *(const s16x8*)(Qr + ((size_t)h * T_SEQ + q0A + w * 16 + lo) * HD + kk * 32 + g * 8);
    qfB[kk] = *(const s16x8*)(Qr + ((size_t)h * T_SEQ + q0B + w * 16 + lo) * HD + kk * 32 + g * 8);
  }
  const int qrA = q0A + w * 16 + lo, qrB = q0B + w * 16 + lo;

  float mA = -3.0e38f, lA = 0.f, mB = -3.0e38f, lB = 0.f;
  f32x4 oA[8] = {}, oB[8] = {};

  auto STAGE = [&](int kvt, int buf) {
#pragma unroll
    for (int p = 0; p < 4; ++p) {
      int ci = p * 256 + tid;
      gload16(Kb + (size_t)(kvt * 64 + (ci >> 4)) * HD + (ci & 15) * 8,
              (char*)(Ks0 + buf * 8192) + ci * 16);
      gload16(Vb + (size_t)(ci >> 3) * TKV + kvt * 64 + (ci & 7) * 8,
              (char*)(Vs0 + buf * 8192) + ci * 16);
    }
  };

  STAGE(0, 0);
  asm volatile("s_waitcnt vmcnt(0)" ::: "memory");
  __syncthreads();

  for (int kvt = 0; kvt < ntB; ++kvt) {
    const int cur = kvt & 1;
    if (kvt + 1 < ntB) STAGE(kvt + 1, cur ^ 1);
    const char* Ksb = (const char*)(Ks0 + cur * 8192);
    const char* Vsb = (const char*)(Vs0 + cur * 8192);
    const bool doA = (kvt < ntA);
    const bool maskA = (kvt == ntA - 1);
    const bool maskB = (kvt == ntB - 1);

    // ---- S phase: shared kf -> both subtiles
    f32x4 sA[4], sB[4];
    __builtin_amdgcn_s_setprio(1);
#pragma unroll
    for (int cj = 0; cj < 4; ++cj) {
      f32x4 zA = {}, zB = {};
      const int kr = cj * 16 + lo;
#pragma unroll
      for (int kk = 0; kk < 4; ++kk) {
        s16x8 kf = *(const s16x8*)(Ksb + ((kr * 256 + kk * 64 + g * 16) ^ ((kr & 7) << 4)));
        zB = __builtin_amdgcn_mfma_f32_16x16x32_bf16(kf, qfB[kk], zB, 0, 0, 0);
        if (doA) zA = __builtin_amdgcn_mfma_f32_16x16x32_bf16(kf, qfA[kk], zA, 0, 0, 0);
      }
      sA[cj] = zA; sB[cj] = zB;
    }
    __builtin_amdgcn_s_setprio(0);

    // ---- softmax per subtile (same math as v4-v6)
#define SOFTMAX(S, M, L, O, PSW, MASKED, QR) { \
      float mx = -3.0e38f; \
      _Pragma("unroll") for (int cj = 0; cj < 4; ++cj) \
      _Pragma("unroll") for (int r = 0; r < 4; ++r) { \
        float s = S[cj][r]; \
        if (MASKED) { \
          int k = kvt * 64 + cj * 16 + g * 4 + r; \
          bool ok = (k < RVIRT) || (k - RVIRT <= (QR)); \
          s = ok ? s : -3.0e38f; S[cj][r] = s; \
        } \
        mx = fmaxf(mx, s); \
      } \
      mx = fmaxf(mx, __shfl_xor(mx, 16, 64)); \
      mx = fmaxf(mx, __shfl_xor(mx, 32, 64)); \
      if (__any(mx > M + 8.0f)) { \
        float mnew = fmaxf(M, mx); \
        float fs = __expf(M - mnew); \
        M = mnew; L *= fs; \
        _Pragma("unroll") for (int r = 0; r < 4; ++r) { \
          float fsq = __shfl(fs, g * 4 + r, 64); \
          _Pragma("unroll") for (int dj = 0; dj < 8; ++dj) O[dj][r] *= fsq; \
        } \
      } \
      float rowsum = 0.f; \
      _Pragma("unroll") for (int cj = 0; cj < 4; ++cj) { \
        s16x4 pk; \
        _Pragma("unroll") for (int r = 0; r < 4; ++r) { \
          float pv = __expf(S[cj][r] - M); \
          rowsum += pv; pk[r] = f2bf(pv); \
        } \
        *(s16x4*)(PSW + ((lo * 128 + cj * 32 + g * 8) ^ ((lo & 7) << 4))) = pk; \
      } \
      rowsum += __shfl_xor(rowsum, 16, 64); \
      rowsum += __shfl_xor(rowsum, 32, 64); \
      L += rowsum; \
    }
    if (doA) SOFTMAX(sA, mA, lA, oA, PsA, maskA, qrA);
    SOFTMAX(sB, mB, lB, oB, PsB, maskB, qrB);
#undef SOFTMAX

    // ---- PV phase: shared vf -> both subtiles
    s16x8 pfA[2], pfB[2];
#pragma unroll
    for (int k2 = 0; k2 < 2; ++k2) {
      pfB[k2] = *(const s16x8*)(PsB + ((lo * 128 + k2 * 64 + g * 16) ^ ((lo & 7) << 4)));
      if (doA) pfA[k2] = *(const s16x8*)(PsA + ((lo * 128 + k2 * 64 + g * 16) ^ ((lo & 7) << 4)));
    }
    __builtin_amdgcn_s_setprio(1);
#pragma unroll
    for (int dj = 0; dj < 8; ++dj) {
      const int d = dj * 16 + lo;
      const int vswz = ((d ^ (d >> 3)) & 7) << 4;
#pragma unroll
      for (int k2 = 0; k2 < 2; ++k2) {
        s16x8 vf = *(const s16x8*)(Vsb + ((d * 128 + k2 * 64 + g * 16) ^ vswz));
        oB[dj] = __builtin_amdgcn_mfma_f32_16x16x32_bf16(pfB[k2], vf, oB[dj], 0, 0, 0);
        if (doA) oA[dj] = __builtin_amdgcn_mfma_f32_16x16x32_bf16(pfA[k2], vf, oA[dj], 0, 0, 0);
      }
    }
    __builtin_amdgcn_s_setprio(0);

    asm volatile("s_waitcnt vmcnt(0)" ::: "memory");  // next-tile loads landed
    __syncthreads();
  }

  // epilogue: o row q = g*4 + r; l lives on lane with lo == q (any g)
#pragma unroll
  for (int r = 0; r < 4; ++r) {
    float lqA = __shfl(lA, g * 4 + r, 64);
    float lqB = __shfl(lB, g * 4 + r, 64);
    float iA = 1.f / lqA, iB = 1.f / lqB;
#pragma unroll
    for (int dj = 0; dj < 8; ++dj) {
      int col = h * HD + dj * 16 + lo;
      int rowA = q0A + w * 16 + g * 4 + r;
      int rowB = q0B + w * 16 + g * 4 + r;
      out[(size_t)rowA * (NH * HD) + col] = f2bf(oA[dj][r] * iA);
      out[(size_t)rowB * (NH * HD) + col] = f2bf(oB[dj][r] * iB);
    }
  }
}

// ---------------------------------------------------------------------------
extern "C" void kernel_launch(void* const* d_in, const int* in_sizes, int n_in,
                              void* d_out, int out_size, void* d_ws, size_t ws_size,
                              hipStream_t stream)
{
  const float* hidden = (const float*)d_in[0];
  // d_in[1] = attention_mask: structurally known (causal + R visible), unused.
  const float* cosT = (const float*)d_in[2];
  const float* sinT = (const float*)d_in[3];
  const float* vk   = (const float*)d_in[4];
  const float* vv   = (const float*)d_in[5];
  const float* Wq   = (const float*)d_in[6];
  const float* Wk   = (const float*)d_in[7];
  const float* Wv   = (const float*)d_in[8];
  const float* Wo   = (const float*)d_in[9];
  const float* qnw  = (const float*)d_in[10];
  const float* knw  = (const float*)d_in[11];
  const float* alog = (const float*)d_in[12];

  char* ws = (char*)d_ws;
  float* q_projf = (float*)ws;                         // 33,554,432 B
  float* k_projf = (float*)(ws + 33554432);            //  8,388,608 B
  short* Vt      = (short*)(ws + 41943040);            //  4,456,448 B
  short* Qr      = (short*)(ws + 46399488);            // 16,777,216 B
  short* Kr      = (short*)(ws + 63176704);            //  4,456,448 B
  short* Xb      = (short*)(ws + 67633152);            // 16,777,216 B
  short* Wall    = (short*)(ws + 84410368);            // 50,331,648 B  (Wq|Wk|Wv)^T
  short* Wot     = Wall;                               // reused after QKV gemm
  short* attn_out = (short*)ws;                        // reuses q_projf (bf16)
  float* outp = (float*)d_out;

  const float qscale = 0.08838834764831845f;           // 128^-0.5

  dim3 blk(256);
  prep_kernel<<<dim3(10240), blk, 0, stream>>>(hidden, Xb, Wq, Wk, Wv, Wall);
  gemm_qkv<<<dim3(32, 8), dim3(512), 0, stream>>>(Xb, Wall, q_projf, k_projf, Vt, DMODEL);
  ropeinj_kernel<<<dim3(20992), blk, 0, stream>>>(q_projf, k_projf, qnw, knw,
      cosT, sinT, vk, vv, alog, Qr, Kr, Vt, qscale);
  attn_wo_kernel<<<dim3(4608), blk, 0, stream>>>(Qr, Kr, Vt, attn_out, Wo, Wot);
  gemm_out<<<dim3(16, 16), dim3(512), 0, stream>>>(attn_out, Wot, outp, 4096);
}

// Round 12
// 319.995 us; speedup vs baseline: 1.0047x; 1.0047x over previous
//
#include <hip/hip_runtime.h>
#include <hip/hip_bf16.h>

#define T_SEQ 2048
#define DMODEL 4096
#define NH 32
#define NKV 8
#define HD 128
#define RVIRT 128
#define TKV (RVIRT + T_SEQ)   // 2176

typedef __attribute__((ext_vector_type(8))) short s16x8;
typedef __attribute__((ext_vector_type(4))) short s16x4;
typedef __attribute__((ext_vector_type(4))) float f32x4;
typedef __attribute__((ext_vector_type(4))) float float4v;

static __device__ __forceinline__ short f2bf(float f) {
  union { __hip_bfloat16 h; short s; } u; u.h = __float2bfloat16(f); return u.s;
}

static __device__ __forceinline__ void gload16(const void* g, void* l) {
  __builtin_amdgcn_global_load_lds(
      (const __attribute__((address_space(1))) void*)g,
      (__attribute__((address_space(3))) void*)l, 16, 0, 0);
}

#define TOPSYNC() \
  __builtin_amdgcn_s_barrier(); \
  asm volatile("s_waitcnt lgkmcnt(0)" ::: "memory"); \
  __builtin_amdgcn_sched_barrier(0);

// ---------------------------------------------------------------------------
// prep_kernel: fused {convert_x | transpose Wq | transpose Wk | transpose Wv}.
// ---------------------------------------------------------------------------
__global__ __launch_bounds__(256) void prep_kernel(const float* __restrict__ hidden,
    short* __restrict__ Xb, const float* __restrict__ Wq,
    const float* __restrict__ Wk, const float* __restrict__ Wv,
    short* __restrict__ Wall)
{
  const int bid = blockIdx.x, tid = threadIdx.x;
  if (bid < 4096) {
    int i = (bid * 256 + tid) * 8;
    float4v a = *(const float4v*)(hidden + i);
    float4v b = *(const float4v*)(hidden + i + 4);
    s16x8 o;
#pragma unroll
    for (int j = 0; j < 4; ++j) { o[j] = f2bf(a[j]); o[4 + j] = f2bf(b[j]); }
    *(s16x8*)(Xb + i) = o;
    return;
  }
  // transpose+convert branch
  __shared__ float tile[64][65];
  const float* src; short* dst; int N, k0, n0;
  if (bid < 8192) {
    int b = bid - 4096; src = Wq; dst = Wall; N = 4096;
    n0 = (b & 63) * 64; k0 = (b >> 6) * 64;
  } else if (bid < 9216) {
    int b = bid - 8192; src = Wk; dst = Wall + (size_t)4096 * DMODEL; N = 1024;
    n0 = (b & 15) * 64; k0 = (b >> 4) * 64;
  } else {
    int b = bid - 9216; src = Wv; dst = Wall + (size_t)5120 * DMODEL; N = 1024;
    n0 = (b & 15) * 64; k0 = (b >> 4) * 64;
  }
  const int K = DMODEL;
  const int rr = tid >> 4, c4 = (tid & 15) * 4;
#pragma unroll
  for (int it = 0; it < 4; ++it) {
    int row = it * 16 + rr;
    float4v v = *(const float4v*)(src + (size_t)(k0 + row) * N + n0 + c4);
    tile[row][c4] = v[0]; tile[row][c4 + 1] = v[1];
    tile[row][c4 + 2] = v[2]; tile[row][c4 + 3] = v[3];
  }
  __syncthreads();
  const int n = tid >> 3, seg = tid & 7;
#pragma unroll
  for (int it = 0; it < 2; ++it) {
    int nn = it * 32 + n;
    s16x8 o;
#pragma unroll
    for (int j = 0; j < 8; ++j) o[j] = f2bf(tile[seg * 8 + j][nn]);
    *(s16x8*)(dst + (size_t)(n0 + nn) * K + k0 + seg * 8) = o;
  }
}

// ---------------------------------------------------------------------------
// gemm_qkv: 256x192 tile, 8 waves (4M x 2N), BK=64, 3 phases/K-tile.
// Grid 8x32 = 256 blocks = 100% CU fill. (r10 staging/waits: proven best;
// r11's slack-max variant regressed and was reverted.)
// Cv (V^T) output stored PRE-SWIZZLED for attn's global_load_lds staging.
// ---------------------------------------------------------------------------
__global__ __launch_bounds__(512, 2) void gemm_qkv(const short* __restrict__ Ab,
    const short* __restrict__ Btb, float* __restrict__ C0,
    float* __restrict__ Ck, short* __restrict__ Cv, int K)
{
  constexpr int SLOT = 57344;           // 32KB A + 24KB B
  __shared__ __align__(16) char lds[2 * SLOT];
  const int tid = threadIdx.x, lane = tid & 63, w = tid >> 6;
  const int lo = lane & 15, g = lane >> 4;
  const int wm = w >> 1, wn = w & 1;    // 4M x 2N
  const int m0 = blockIdx.y * 256, n0 = blockIdx.x * 192;
  const int NT = K >> 6;
  const int aswz = (lo & 7) << 4;
  const int t8 = tid >> 3, t7 = tid & 7;
  const int swc = (t7 ^ (t8 & 7)) * 8;  // shorts, pre-swizzled col

  const short* As = Ab + (size_t)(m0 + t8) * K + swc;
  const short* Bs[3];
#pragma unroll
  for (int jj = 0; jj < 3; ++jj) {
    int row = (t8 >> 5) * 96 + (2 * jj + ((t8 >> 4) & 1)) * 16 + (t8 & 15);
    Bs[jj] = Btb + (size_t)(n0 + row) * K + swc;
  }
  auto SA = [&](char* nb, int jj, int y) {
    gload16(As + (size_t)jj * 64 * K + y * 64, nb + tid * 16 + jj * 8192);
  };
  auto SB = [&](char* nb, int jj, int y) {
    gload16(Bs[jj] + y * 64, nb + 32768 + tid * 16 + jj * 8192);
  };

  f32x4 acc[4][6];
#pragma unroll
  for (int i = 0; i < 4; ++i)
#pragma unroll
    for (int j = 0; j < 6; ++j) acc[i][j] = (f32x4){0.f, 0.f, 0.f, 0.f};

  s16x8 a[4][2], bq[2][2];

#define QLDB(P) \
  _Pragma("unroll") for (int jj = 0; jj < 2; ++jj) \
  _Pragma("unroll") for (int kk = 0; kk < 2; ++kk) \
    bq[jj][kk] = *(const s16x8*)(bu + 32768 + ((P) * 64 + wn * 32 + jj * 16 + lo) * 128 + ((kk * 64 + g * 16) ^ aswz));
#define QMMQ(P) \
  __builtin_amdgcn_s_setprio(1); \
  _Pragma("unroll") for (int i = 0; i < 4; ++i) \
  _Pragma("unroll") for (int jj = 0; jj < 2; ++jj) { \
    f32x4 z = __builtin_amdgcn_mfma_f32_16x16x32_bf16(a[i][0], bq[jj][0], acc[i][(P) * 2 + jj], 0, 0, 0); \
    acc[i][(P) * 2 + jj] = __builtin_amdgcn_mfma_f32_16x16x32_bf16(a[i][1], bq[jj][1], z, 0, 0, 0); \
  } \
  __builtin_amdgcn_s_setprio(0);

  // prologue: tile 0 fully staged
  SA(lds, 0, 0); SA(lds, 1, 0); SA(lds, 2, 0); SA(lds, 3, 0);
  SB(lds, 0, 0); SB(lds, 1, 0); SB(lds, 2, 0);
  asm volatile("s_waitcnt vmcnt(0)" ::: "memory");
  __builtin_amdgcn_s_barrier();

  for (int t = 0; t < NT; ++t) {
    const char* bu = lds + (t & 1) * SLOT;
    char* nb = lds + ((t + 1) & 1) * SLOT;
    const bool pre = (t + 1 < NT);
    // ---- ph0: cols 0,1
#pragma unroll
    for (int i = 0; i < 4; ++i)
#pragma unroll
      for (int kk = 0; kk < 2; ++kk)
        a[i][kk] = *(const s16x8*)(bu + (wm * 64 + i * 16 + lo) * 128 + ((kk * 64 + g * 16) ^ aswz));
    QLDB(0);
    if (pre) { SA(nb, 0, t + 1); SA(nb, 1, t + 1); SA(nb, 2, t + 1); }
    TOPSYNC();
    QMMQ(0);
    if (pre) asm volatile("s_waitcnt vmcnt(4)" ::: "memory");
    else     asm volatile("s_waitcnt vmcnt(1)" ::: "memory");
    __builtin_amdgcn_s_barrier();
    // ---- ph1: cols 2,3
    QLDB(1);
    if (pre) { SA(nb, 3, t + 1); SB(nb, 0, t + 1); }
    TOPSYNC();
    QMMQ(1);
    if (pre) asm volatile("s_waitcnt vmcnt(5)" ::: "memory");
    else     asm volatile("s_waitcnt vmcnt(0)" ::: "memory");
    __builtin_amdgcn_s_barrier();
    // ---- ph2: cols 4,5
    QLDB(2);
    if (pre) { SB(nb, 1, t + 1); SB(nb, 2, t + 1); }
    TOPSYNC();
    QMMQ(2);
    if (pre) asm volatile("s_waitcnt vmcnt(2)" ::: "memory");
    __builtin_amdgcn_s_barrier();
  }
#undef QLDB
#undef QMMQ

#pragma unroll
  for (int i = 0; i < 4; ++i)
#pragma unroll
    for (int j = 0; j < 6; ++j)
#pragma unroll
      for (int r = 0; r < 4; ++r) {
        int row = m0 + wm * 64 + i * 16 + g * 4 + r;
        int col = n0 + wn * 96 + j * 16 + lo;
        float val = acc[i][j][r];
        if (col < 4096) C0[(size_t)row * 4096 + col] = val;
        else if (col < 5120) Ck[(size_t)row * 1024 + (col - 4096)] = val;
        else {
          int vcol = col - 5120;
          int d = vcol & 127;
          int rp = (RVIRT + row) ^ ((((d >> 3) ^ d) & 7) << 3);
          Cv[((size_t)(vcol >> 7) * HD + d) * TKV + rp] = f2bf(val);
        }
      }
}

// ---------------------------------------------------------------------------
// gemm_out: 128x256 tile, 8 waves (2M x 4N), BK=64, 2 phases/K-tile.
// Grid 16x16 = 256 blocks = 100% fill. (r10 staging/waits restored.)
// ---------------------------------------------------------------------------
__global__ __launch_bounds__(512, 2) void gemm_out(const short* __restrict__ Ab,
    const short* __restrict__ Btb, float* __restrict__ C0, int K)
{
  constexpr int SLOT = 49152;           // 16KB A + 32KB B
  __shared__ __align__(16) char lds[2 * SLOT];
  const int tid = threadIdx.x, lane = tid & 63, w = tid >> 6;
  const int lo = lane & 15, g = lane >> 4;
  const int wm = w >> 2, wn = w & 3;    // 2M x 4N
  const int m0 = blockIdx.y * 128, n0 = blockIdx.x * 256;
  const int NT = K >> 6;
  const int aswz = (lo & 7) << 4;
  const int t8 = tid >> 3, t7 = tid & 7;
  const int swc = (t7 ^ (t8 & 7)) * 8;  // shorts

  const short* As = Ab + (size_t)(m0 + t8) * K + swc;
  const short* Bs[4];
#pragma unroll
  for (int jj = 0; jj < 4; ++jj) {
    int row = (t8 >> 4) * 64 + jj * 16 + (t8 & 15);
    Bs[jj] = Btb + (size_t)(n0 + row) * K + swc;
  }
  auto SA = [&](char* nb, int jj, int y) {
    gload16(As + (size_t)jj * 64 * K + y * 64, nb + tid * 16 + jj * 8192);
  };
  auto SB = [&](char* nb, int jj, int y) {
    gload16(Bs[jj] + y * 64, nb + 16384 + tid * 16 + jj * 8192);
  };

  f32x4 acc[4][4];
#pragma unroll
  for (int i = 0; i < 4; ++i)
#pragma unroll
    for (int j = 0; j < 4; ++j) acc[i][j] = (f32x4){0.f, 0.f, 0.f, 0.f};

  s16x8 a[4][2], bq[2][2];

#define OLDB(P) \
  _Pragma("unroll") for (int jj = 0; jj < 2; ++jj) \
  _Pragma("unroll") for (int kk = 0; kk < 2; ++kk) \
    bq[jj][kk] = *(const s16x8*)(bu + 16384 + (((P) * 2 + jj) * 64 + wn * 16 + lo) * 128 + ((kk * 64 + g * 16) ^ aswz));
#define OMMQ(P) \
  __builtin_amdgcn_s_setprio(1); \
  _Pragma("unroll") for (int i = 0; i < 4; ++i) \
  _Pragma("unroll") for (int jj = 0; jj < 2; ++jj) { \
    f32x4 z = __builtin_amdgcn_mfma_f32_16x16x32_bf16(a[i][0], bq[jj][0], acc[i][(P) * 2 + jj], 0, 0, 0); \
    acc[i][(P) * 2 + jj] = __builtin_amdgcn_mfma_f32_16x16x32_bf16(a[i][1], bq[jj][1], z, 0, 0, 0); \
  } \
  __builtin_amdgcn_s_setprio(0);

  SA(lds, 0, 0); SA(lds, 1, 0);
  SB(lds, 0, 0); SB(lds, 1, 0); SB(lds, 2, 0); SB(lds, 3, 0);
  asm volatile("s_waitcnt vmcnt(0)" ::: "memory");
  __builtin_amdgcn_s_barrier();

  for (int t = 0; t < NT; ++t) {
    const char* bu = lds + (t & 1) * SLOT;
    char* nb = lds + ((t + 1) & 1) * SLOT;
    const bool pre = (t + 1 < NT);
    // ---- ph0: cols 0,1
#pragma unroll
    for (int i = 0; i < 4; ++i)
#pragma unroll
      for (int kk = 0; kk < 2; ++kk)
        a[i][kk] = *(const s16x8*)(bu + (wm * 64 + i * 16 + lo) * 128 + ((kk * 64 + g * 16) ^ aswz));
    OLDB(0);
    if (pre) { SA(nb, 0, t + 1); SA(nb, 1, t + 1); SB(nb, 0, t + 1); SB(nb, 1, t + 1); }
    TOPSYNC();
    OMMQ(0);
    if (pre) asm volatile("s_waitcnt vmcnt(4)" ::: "memory");
    else     asm volatile("s_waitcnt vmcnt(0)" ::: "memory");
    __builtin_amdgcn_s_barrier();
    // ---- ph1: cols 2,3
    OLDB(1);
    if (pre) { SB(nb, 2, t + 1); SB(nb, 3, t + 1); }
    TOPSYNC();
    OMMQ(1);
    if (pre) asm volatile("s_waitcnt vmcnt(2)" ::: "memory");
    __builtin_amdgcn_s_barrier();
  }
#undef OLDB
#undef OMMQ

#pragma unroll
  for (int i = 0; i < 4; ++i)
#pragma unroll
    for (int j = 0; j < 4; ++j)
#pragma unroll
      for (int r = 0; r < 4; ++r) {
        int row = m0 + wm * 64 + i * 16 + g * 4 + r;
        int col = n0 + wn * 64 + j * 16 + lo;
        C0[(size_t)row * 4096 + col] = acc[i][j][r];
      }
}

// ---------------------------------------------------------------------------
// ropeinj_kernel: fused {rope Q | rope K | virtual-KV inject}.
// Q scale additionally folds log2(e) so attn softmax uses bare exp2
// (v_exp is natively base-2; saves the v_mul(log2e) per exp).
// ---------------------------------------------------------------------------
__global__ __launch_bounds__(256) void ropeinj_kernel(
    const float* __restrict__ q_projf, const float* __restrict__ k_projf,
    const float* __restrict__ qnw, const float* __restrict__ knw,
    const float* __restrict__ cosT, const float* __restrict__ sinT,
    const float* __restrict__ vk, const float* __restrict__ vv,
    const float* __restrict__ logit,
    short* __restrict__ Qr, short* __restrict__ Kr, short* __restrict__ Vt,
    float qscale)
{
  const int bid = blockIdx.x, tid = threadIdx.x;
  if (bid < 20480) {
    const float* proj; const float* nw; short* outp;
    int nh_shift, rows_total, row0, kswz; float qs; int wid;
    if (bid < 16384) {
      proj = q_projf; nw = qnw; outp = Qr; nh_shift = 5;
      rows_total = T_SEQ; row0 = 0; qs = qscale; kswz = 0;
      wid = bid * 4 + (tid >> 6);
    } else {
      proj = k_projf; nw = knw; outp = Kr; nh_shift = 3;
      rows_total = TKV; row0 = RVIRT; qs = 1.0f; kswz = 1;
      wid = (bid - 16384) * 4 + (tid >> 6);
    }
    int lane = tid & 63;
    int nh = 1 << nh_shift;
    int t = wid >> nh_shift;
    int hh = wid & (nh - 1);
    const float* src = proj + (size_t)t * (nh * HD) + hh * HD;
    float x1 = src[lane];
    float x2 = src[lane + 64];
    float ss = x1 * x1 + x2 * x2;
#pragma unroll
    for (int off = 32; off > 0; off >>= 1) ss += __shfl_xor(ss, off, 64);
    float rms = rsqrtf(ss * (1.0f / 128.0f) + 1e-6f);
    float n1 = x1 * rms * nw[lane];
    float n2 = x2 * rms * nw[lane + 64];
    float c1 = cosT[t * HD + lane], c2 = cosT[t * HD + lane + 64];
    float s1 = sinT[t * HD + lane], s2 = sinT[t * HD + lane + 64];
    short* dst = outp + ((size_t)hh * rows_total + row0 + t) * HD;
    int sw = kswz ? (((row0 + t) & 7) << 3) : 0;
    dst[lane ^ sw]        = f2bf((n1 * c1 - n2 * s1) * qs);
    dst[(lane + 64) ^ sw] = f2bf((n2 * c2 + n1 * s2) * qs);
  } else {
    int idx = (bid - 20480) * 256 + tid;   // < 8*128*128
    float alpha = 0.5f / (1.0f + __expf(-logit[0]));
    int kv = idx >> 14, rem = idx & 16383, r = rem >> 7, d = rem & 127;
    int swk = (r & 7) << 3;
    Kr[((size_t)kv * TKV + r) * HD + (d ^ swk)] = f2bf(vk[idx] * alpha);
    int swv = ((d ^ (d >> 3)) & 7) << 3;
    Vt[((size_t)kv * HD + d) * TKV + (r ^ swv)] = f2bf(vv[idx] * alpha);
  }
}

// ---------------------------------------------------------------------------
// attn_wo_kernel: fused {flash attention v6 | transpose Wo}.
// r12: softmax in log2 domain (Q pre-scaled by log2e upstream): exp2f
// replaces __expf (v_exp is base-2 native; saves one v_mul per exp),
// defer-max threshold 8 -> 8*log2e = 11.5415603. Math otherwise identical:
// exp2(log2e*(s-m)) == e^(s-m), so l/o/out values are unchanged.
// ---------------------------------------------------------------------------
__global__ __launch_bounds__(256, 2) void attn_wo_kernel(const short* __restrict__ Qr,
    const short* __restrict__ Kr, const short* __restrict__ Vt,
    short* __restrict__ out, const float* __restrict__ Wo,
    short* __restrict__ Wot)
{
  __shared__ __align__(16) char smem[81920];
  const int tid = threadIdx.x;
  const int bid = blockIdx.x;

  if (bid >= 512) {
    // ---------------- Wo transpose branch ----------------
    float* tile = (float*)smem;               // [64][65]
    int b = bid - 512;
    const int n0 = (b & 63) * 64, k0 = (b >> 6) * 64;
    const int N = 4096, K = 4096;
    const int rr = tid >> 4, c4 = (tid & 15) * 4;
#pragma unroll
    for (int it = 0; it < 4; ++it) {
      int row = it * 16 + rr;
      float4v v = *(const float4v*)(Wo + (size_t)(k0 + row) * N + n0 + c4);
      tile[row * 65 + c4] = v[0]; tile[row * 65 + c4 + 1] = v[1];
      tile[row * 65 + c4 + 2] = v[2]; tile[row * 65 + c4 + 3] = v[3];
    }
    __syncthreads();
    const int n = tid >> 3, seg = tid & 7;
#pragma unroll
    for (int it = 0; it < 2; ++it) {
      int nn = it * 32 + n;
      s16x8 o;
#pragma unroll
      for (int j = 0; j < 8; ++j) o[j] = f2bf(tile[(seg * 8 + j) * 65 + nn]);
      *(s16x8*)(Wot + (size_t)(n0 + nn) * K + k0 + seg * 8) = o;
    }
    return;
  }

  // ---------------- attention v6 branch ----------------
  short* Ks0 = (short*)smem;                  // [2][64*128]
  short* Vs0 = (short*)(smem + 32768);        // [2][128*64]
  char*  Ps  = smem + 65536;                  // per wave: 2KB A + 2KB B
  const int lane = tid & 63, w = tid >> 6;
  const int kvh = bid & 7;                    // XCD-aligned kv-head
  const int r5 = bid >> 3;
  const int h = kvh * 4 + (r5 & 3);
  const int bx = r5 >> 2;                     // 0..15
  const int lo = lane & 15, g = lane >> 4;
  const int q0A = bx * 64, q0B = (31 - bx) * 64;
  const int ntA = bx + 3, ntB = 34 - bx;
  char* PsA = Ps + w * 4096;
  char* PsB = PsA + 2048;
  const short* Kb = Kr + (size_t)kvh * TKV * HD;
  const short* Vb = Vt + (size_t)kvh * HD * TKV;

  s16x8 qfA[4], qfB[4];
#pragma unroll
  for (int kk = 0; kk < 4; ++kk) {
    qfA[kk] = *(const s16x8*)(Qr + ((size_t)h * T_SEQ + q0A + w * 16 + lo) * HD + kk * 32 + g * 8);
    qfB[kk] = *(const s16x8*)(Qr + ((size_t)h * T_SEQ + q0B + w * 16 + lo) * HD + kk * 32 + g * 8);
  }
  const int qrA = q0A + w * 16 + lo, qrB = q0B + w * 16 + lo;

  float mA = -3.0e38f, lA = 0.f, mB = -3.0e38f, lB = 0.f;
  f32x4 oA[8] = {}, oB[8] = {};

  auto STAGE = [&](int kvt, int buf) {
#pragma unroll
    for (int p = 0; p < 4; ++p) {
      int ci = p * 256 + tid;
      gload16(Kb + (size_t)(kvt * 64 + (ci >> 4)) * HD + (ci & 15) * 8,
              (char*)(Ks0 + buf * 8192) + ci * 16);
      gload16(Vb + (size_t)(ci >> 3) * TKV + kvt * 64 + (ci & 7) * 8,
              (char*)(Vs0 + buf * 8192) + ci * 16);
    }
  };

  STAGE(0, 0);
  asm volatile("s_waitcnt vmcnt(0)" ::: "memory");
  __syncthreads();

  for (int kvt = 0; kvt < ntB; ++kvt) {
    const int cur = kvt & 1;
    if (kvt + 1 < ntB) STAGE(kvt + 1, cur ^ 1);
    const char* Ksb = (const char*)(Ks0 + cur * 8192);
    const char* Vsb = (const char*)(Vs0 + cur * 8192);
    const bool doA = (kvt < ntA);
    const bool maskA = (kvt == ntA - 1);
    const bool maskB = (kvt == ntB - 1);

    // ---- S phase: shared kf -> both subtiles
    f32x4 sA[4], sB[4];
    __builtin_amdgcn_s_setprio(1);
#pragma unroll
    for (int cj = 0; cj < 4; ++cj) {
      f32x4 zA = {}, zB = {};
      const int kr = cj * 16 + lo;
#pragma unroll
      for (int kk = 0; kk < 4; ++kk) {
        s16x8 kf = *(const s16x8*)(Ksb + ((kr * 256 + kk * 64 + g * 16) ^ ((kr & 7) << 4)));
        zB = __builtin_amdgcn_mfma_f32_16x16x32_bf16(kf, qfB[kk], zB, 0, 0, 0);
        if (doA) zA = __builtin_amdgcn_mfma_f32_16x16x32_bf16(kf, qfA[kk], zA, 0, 0, 0);
      }
      sA[cj] = zA; sB[cj] = zB;
    }
    __builtin_amdgcn_s_setprio(0);

    // ---- softmax per subtile (log2-domain: S already scaled by log2e)
#define SOFTMAX(S, M, L, O, PSW, MASKED, QR) { \
      float mx = -3.0e38f; \
      _Pragma("unroll") for (int cj = 0; cj < 4; ++cj) \
      _Pragma("unroll") for (int r = 0; r < 4; ++r) { \
        float s = S[cj][r]; \
        if (MASKED) { \
          int k = kvt * 64 + cj * 16 + g * 4 + r; \
          bool ok = (k < RVIRT) || (k - RVIRT <= (QR)); \
          s = ok ? s : -3.0e38f; S[cj][r] = s; \
        } \
        mx = fmaxf(mx, s); \
      } \
      mx = fmaxf(mx, __shfl_xor(mx, 16, 64)); \
      mx = fmaxf(mx, __shfl_xor(mx, 32, 64)); \
      if (__any(mx > M + 11.541560327111707f)) { \
        float mnew = fmaxf(M, mx); \
        float fs = exp2f(M - mnew); \
        M = mnew; L *= fs; \
        _Pragma("unroll") for (int r = 0; r < 4; ++r) { \
          float fsq = __shfl(fs, g * 4 + r, 64); \
          _Pragma("unroll") for (int dj = 0; dj < 8; ++dj) O[dj][r] *= fsq; \
        } \
      } \
      float rowsum = 0.f; \
      _Pragma("unroll") for (int cj = 0; cj < 4; ++cj) { \
        s16x4 pk; \
        _Pragma("unroll") for (int r = 0; r < 4; ++r) { \
          float pv = exp2f(S[cj][r] - M); \
          rowsum += pv; pk[r] = f2bf(pv); \
        } \
        *(s16x4*)(PSW + ((lo * 128 + cj * 32 + g * 8) ^ ((lo & 7) << 4))) = pk; \
      } \
      rowsum += __shfl_xor(rowsum, 16, 64); \
      rowsum += __shfl_xor(rowsum, 32, 64); \
      L += rowsum; \
    }
    if (doA) SOFTMAX(sA, mA, lA, oA, PsA, maskA, qrA);
    SOFTMAX(sB, mB, lB, oB, PsB, maskB, qrB);
#undef SOFTMAX

    // ---- PV phase: shared vf -> both subtiles
    s16x8 pfA[2], pfB[2];
#pragma unroll
    for (int k2 = 0; k2 < 2; ++k2) {
      pfB[k2] = *(const s16x8*)(PsB + ((lo * 128 + k2 * 64 + g * 16) ^ ((lo & 7) << 4)));
      if (doA) pfA[k2] = *(const s16x8*)(PsA + ((lo * 128 + k2 * 64 + g * 16) ^ ((lo & 7) << 4)));
    }
    __builtin_amdgcn_s_setprio(1);
#pragma unroll
    for (int dj = 0; dj < 8; ++dj) {
      const int d = dj * 16 + lo;
      const int vswz = ((d ^ (d >> 3)) & 7) << 4;
#pragma unroll
      for (int k2 = 0; k2 < 2; ++k2) {
        s16x8 vf = *(const s16x8*)(Vsb + ((d * 128 + k2 * 64 + g * 16) ^ vswz));
        oB[dj] = __builtin_amdgcn_mfma_f32_16x16x32_bf16(pfB[k2], vf, oB[dj], 0, 0, 0);
        if (doA) oA[dj] = __builtin_amdgcn_mfma_f32_16x16x32_bf16(pfA[k2], vf, oA[dj], 0, 0, 0);
      }
    }
    __builtin_amdgcn_s_setprio(0);

    asm volatile("s_waitcnt vmcnt(0)" ::: "memory");  // next-tile loads landed
    __syncthreads();
  }

  // epilogue: o row q = g*4 + r; l lives on lane with lo == q (any g)
#pragma unroll
  for (int r = 0; r < 4; ++r) {
    float lqA = __shfl(lA, g * 4 + r, 64);
    float lqB = __shfl(lB, g * 4 + r, 64);
    float iA = 1.f / lqA, iB = 1.f / lqB;
#pragma unroll
    for (int dj = 0; dj < 8; ++dj) {
      int col = h * HD + dj * 16 + lo;
      int rowA = q0A + w * 16 + g * 4 + r;
      int rowB = q0B + w * 16 + g * 4 + r;
      out[(size_t)rowA * (NH * HD) + col] = f2bf(oA[dj][r] * iA);
      out[(size_t)rowB * (NH * HD) + col] = f2bf(oB[dj][r] * iB);
    }
  }
}

// ---------------------------------------------------------------------------
extern "C" void kernel_launch(void* const* d_in, const int* in_sizes, int n_in,
                              void* d_out, int out_size, void* d_ws, size_t ws_size,
                              hipStream_t stream)
{
  const float* hidden = (const float*)d_in[0];
  // d_in[1] = attention_mask: structurally known (causal + R visible), unused.
  const float* cosT = (const float*)d_in[2];
  const float* sinT = (const float*)d_in[3];
  const float* vk   = (const float*)d_in[4];
  const float* vv   = (const float*)d_in[5];
  const float* Wq   = (const float*)d_in[6];
  const float* Wk   = (const float*)d_in[7];
  const float* Wv   = (const float*)d_in[8];
  const float* Wo   = (const float*)d_in[9];
  const float* qnw  = (const float*)d_in[10];
  const float* knw  = (const float*)d_in[11];
  const float* alog = (const float*)d_in[12];

  char* ws = (char*)d_ws;
  float* q_projf = (float*)ws;                         // 33,554,432 B
  float* k_projf = (float*)(ws + 33554432);            //  8,388,608 B
  short* Vt      = (short*)(ws + 41943040);            //  4,456,448 B
  short* Qr      = (short*)(ws + 46399488);            // 16,777,216 B
  short* Kr      = (short*)(ws + 63176704);            //  4,456,448 B
  short* Xb      = (short*)(ws + 67633152);            // 16,777,216 B
  short* Wall    = (short*)(ws + 84410368);            // 50,331,648 B  (Wq|Wk|Wv)^T
  short* Wot     = Wall;                               // reused after QKV gemm
  short* attn_out = (short*)ws;                        // reuses q_projf (bf16)
  float* outp = (float*)d_out;

  // 128^-0.5 * log2(e): attn softmax runs in log2 domain (bare v_exp).
  const float qscale = 0.12751741826167906f;

  dim3 blk(256);
  prep_kernel<<<dim3(10240), blk, 0, stream>>>(hidden, Xb, Wq, Wk, Wv, Wall);
  gemm_qkv<<<dim3(32, 8), dim3(512), 0, stream>>>(Xb, Wall, q_projf, k_projf, Vt, DMODEL);
  ropeinj_kernel<<<dim3(20992), blk, 0, stream>>>(q_projf, k_projf, qnw, knw,
      cosT, sinT, vk, vv, alog, Qr, Kr, Vt, qscale);
  attn_wo_kernel<<<dim3(4608), blk, 0, stream>>>(Qr, Kr, Vt, attn_out, Wo, Wot);
  gemm_out<<<dim3(16, 16), dim3(512), 0, stream>>>(attn_out, Wot, outp, 4096);
}

// Round 13
// 314.375 us; speedup vs baseline: 1.0226x; 1.0179x over previous
//
#include <hip/hip_runtime.h>
#include <hip/hip_bf16.h>

#define T_SEQ 2048
#define DMODEL 4096
#define NH 32
#define NKV 8
#define HD 128
#define RVIRT 128
#define TKV (RVIRT + T_SEQ)   // 2176

typedef __attribute__((ext_vector_type(8))) short s16x8;
typedef __attribute__((ext_vector_type(4))) short s16x4;
typedef __attribute__((ext_vector_type(4))) float f32x4;
typedef __attribute__((ext_vector_type(4))) float float4v;

static __device__ __forceinline__ short f2bf(float f) {
  union { __hip_bfloat16 h; short s; } u; u.h = __float2bfloat16(f); return u.s;
}

static __device__ __forceinline__ void gload16(const void* g, void* l) {
  __builtin_amdgcn_global_load_lds(
      (const __attribute__((address_space(1))) void*)g,
      (__attribute__((address_space(3))) void*)l, 16, 0, 0);
}

#define TOPSYNC() \
  __builtin_amdgcn_s_barrier(); \
  asm volatile("s_waitcnt lgkmcnt(0)" ::: "memory"); \
  __builtin_amdgcn_sched_barrier(0);

// ---------------------------------------------------------------------------
// prep_kernel: fused {convert_x | transpose Wq | transpose Wk | transpose Wv}.
// ---------------------------------------------------------------------------
__global__ __launch_bounds__(256) void prep_kernel(const float* __restrict__ hidden,
    short* __restrict__ Xb, const float* __restrict__ Wq,
    const float* __restrict__ Wk, const float* __restrict__ Wv,
    short* __restrict__ Wall)
{
  const int bid = blockIdx.x, tid = threadIdx.x;
  if (bid < 4096) {
    int i = (bid * 256 + tid) * 8;
    float4v a = *(const float4v*)(hidden + i);
    float4v b = *(const float4v*)(hidden + i + 4);
    s16x8 o;
#pragma unroll
    for (int j = 0; j < 4; ++j) { o[j] = f2bf(a[j]); o[4 + j] = f2bf(b[j]); }
    *(s16x8*)(Xb + i) = o;
    return;
  }
  // transpose+convert branch
  __shared__ float tile[64][65];
  const float* src; short* dst; int N, k0, n0;
  if (bid < 8192) {
    int b = bid - 4096; src = Wq; dst = Wall; N = 4096;
    n0 = (b & 63) * 64; k0 = (b >> 6) * 64;
  } else if (bid < 9216) {
    int b = bid - 8192; src = Wk; dst = Wall + (size_t)4096 * DMODEL; N = 1024;
    n0 = (b & 15) * 64; k0 = (b >> 4) * 64;
  } else {
    int b = bid - 9216; src = Wv; dst = Wall + (size_t)5120 * DMODEL; N = 1024;
    n0 = (b & 15) * 64; k0 = (b >> 4) * 64;
  }
  const int K = DMODEL;
  const int rr = tid >> 4, c4 = (tid & 15) * 4;
#pragma unroll
  for (int it = 0; it < 4; ++it) {
    int row = it * 16 + rr;
    float4v v = *(const float4v*)(src + (size_t)(k0 + row) * N + n0 + c4);
    tile[row][c4] = v[0]; tile[row][c4 + 1] = v[1];
    tile[row][c4 + 2] = v[2]; tile[row][c4 + 3] = v[3];
  }
  __syncthreads();
  const int n = tid >> 3, seg = tid & 7;
#pragma unroll
  for (int it = 0; it < 2; ++it) {
    int nn = it * 32 + n;
    s16x8 o;
#pragma unroll
    for (int j = 0; j < 8; ++j) o[j] = f2bf(tile[seg * 8 + j][nn]);
    *(s16x8*)(dst + (size_t)(n0 + nn) * K + k0 + seg * 8) = o;
  }
}

// ---------------------------------------------------------------------------
// gemm_qkv: 256x192 tile, 8 waves (4M x 2N), BK=64, 3 phases/K-tile.
// Grid 8x32 = 256 blocks = 100% CU fill. (r10 staging/waits: proven best.)
// Cv (V^T) output stored PRE-SWIZZLED for attn's global_load_lds staging.
// ---------------------------------------------------------------------------
__global__ __launch_bounds__(512, 2) void gemm_qkv(const short* __restrict__ Ab,
    const short* __restrict__ Btb, float* __restrict__ C0,
    float* __restrict__ Ck, short* __restrict__ Cv, int K)
{
  constexpr int SLOT = 57344;           // 32KB A + 24KB B
  __shared__ __align__(16) char lds[2 * SLOT];
  const int tid = threadIdx.x, lane = tid & 63, w = tid >> 6;
  const int lo = lane & 15, g = lane >> 4;
  const int wm = w >> 1, wn = w & 1;    // 4M x 2N
  const int m0 = blockIdx.y * 256, n0 = blockIdx.x * 192;
  const int NT = K >> 6;
  const int aswz = (lo & 7) << 4;
  const int t8 = tid >> 3, t7 = tid & 7;
  const int swc = (t7 ^ (t8 & 7)) * 8;  // shorts, pre-swizzled col

  const short* As = Ab + (size_t)(m0 + t8) * K + swc;
  const short* Bs[3];
#pragma unroll
  for (int jj = 0; jj < 3; ++jj) {
    int row = (t8 >> 5) * 96 + (2 * jj + ((t8 >> 4) & 1)) * 16 + (t8 & 15);
    Bs[jj] = Btb + (size_t)(n0 + row) * K + swc;
  }
  auto SA = [&](char* nb, int jj, int y) {
    gload16(As + (size_t)jj * 64 * K + y * 64, nb + tid * 16 + jj * 8192);
  };
  auto SB = [&](char* nb, int jj, int y) {
    gload16(Bs[jj] + y * 64, nb + 32768 + tid * 16 + jj * 8192);
  };

  f32x4 acc[4][6];
#pragma unroll
  for (int i = 0; i < 4; ++i)
#pragma unroll
    for (int j = 0; j < 6; ++j) acc[i][j] = (f32x4){0.f, 0.f, 0.f, 0.f};

  s16x8 a[4][2], bq[2][2];

#define QLDB(P) \
  _Pragma("unroll") for (int jj = 0; jj < 2; ++jj) \
  _Pragma("unroll") for (int kk = 0; kk < 2; ++kk) \
    bq[jj][kk] = *(const s16x8*)(bu + 32768 + ((P) * 64 + wn * 32 + jj * 16 + lo) * 128 + ((kk * 64 + g * 16) ^ aswz));
#define QMMQ(P) \
  __builtin_amdgcn_s_setprio(1); \
  _Pragma("unroll") for (int i = 0; i < 4; ++i) \
  _Pragma("unroll") for (int jj = 0; jj < 2; ++jj) { \
    f32x4 z = __builtin_amdgcn_mfma_f32_16x16x32_bf16(a[i][0], bq[jj][0], acc[i][(P) * 2 + jj], 0, 0, 0); \
    acc[i][(P) * 2 + jj] = __builtin_amdgcn_mfma_f32_16x16x32_bf16(a[i][1], bq[jj][1], z, 0, 0, 0); \
  } \
  __builtin_amdgcn_s_setprio(0);

  // prologue: tile 0 fully staged
  SA(lds, 0, 0); SA(lds, 1, 0); SA(lds, 2, 0); SA(lds, 3, 0);
  SB(lds, 0, 0); SB(lds, 1, 0); SB(lds, 2, 0);
  asm volatile("s_waitcnt vmcnt(0)" ::: "memory");
  __builtin_amdgcn_s_barrier();

  for (int t = 0; t < NT; ++t) {
    const char* bu = lds + (t & 1) * SLOT;
    char* nb = lds + ((t + 1) & 1) * SLOT;
    const bool pre = (t + 1 < NT);
    // ---- ph0: cols 0,1
#pragma unroll
    for (int i = 0; i < 4; ++i)
#pragma unroll
      for (int kk = 0; kk < 2; ++kk)
        a[i][kk] = *(const s16x8*)(bu + (wm * 64 + i * 16 + lo) * 128 + ((kk * 64 + g * 16) ^ aswz));
    QLDB(0);
    if (pre) { SA(nb, 0, t + 1); SA(nb, 1, t + 1); SA(nb, 2, t + 1); }
    TOPSYNC();
    QMMQ(0);
    if (pre) asm volatile("s_waitcnt vmcnt(4)" ::: "memory");
    else     asm volatile("s_waitcnt vmcnt(1)" ::: "memory");
    __builtin_amdgcn_s_barrier();
    // ---- ph1: cols 2,3
    QLDB(1);
    if (pre) { SA(nb, 3, t + 1); SB(nb, 0, t + 1); }
    TOPSYNC();
    QMMQ(1);
    if (pre) asm volatile("s_waitcnt vmcnt(5)" ::: "memory");
    else     asm volatile("s_waitcnt vmcnt(0)" ::: "memory");
    __builtin_amdgcn_s_barrier();
    // ---- ph2: cols 4,5
    QLDB(2);
    if (pre) { SB(nb, 1, t + 1); SB(nb, 2, t + 1); }
    TOPSYNC();
    QMMQ(2);
    if (pre) asm volatile("s_waitcnt vmcnt(2)" ::: "memory");
    __builtin_amdgcn_s_barrier();
  }
#undef QLDB
#undef QMMQ

#pragma unroll
  for (int i = 0; i < 4; ++i)
#pragma unroll
    for (int j = 0; j < 6; ++j)
#pragma unroll
      for (int r = 0; r < 4; ++r) {
        int row = m0 + wm * 64 + i * 16 + g * 4 + r;
        int col = n0 + wn * 96 + j * 16 + lo;
        float val = acc[i][j][r];
        if (col < 4096) C0[(size_t)row * 4096 + col] = val;
        else if (col < 5120) Ck[(size_t)row * 1024 + (col - 4096)] = val;
        else {
          int vcol = col - 5120;
          int d = vcol & 127;
          int rp = (RVIRT + row) ^ ((((d >> 3) ^ d) & 7) << 3);
          Cv[((size_t)(vcol >> 7) * HD + d) * TKV + rp] = f2bf(val);
        }
      }
}

// ---------------------------------------------------------------------------
// gemm_out: 128x256 tile, 8 waves (2M x 4N), BK=64, 2 phases/K-tile.
// Grid 16x16 = 256 blocks = 100% fill. (r10 staging/waits.)
// ---------------------------------------------------------------------------
__global__ __launch_bounds__(512, 2) void gemm_out(const short* __restrict__ Ab,
    const short* __restrict__ Btb, float* __restrict__ C0, int K)
{
  constexpr int SLOT = 49152;           // 16KB A + 32KB B
  __shared__ __align__(16) char lds[2 * SLOT];
  const int tid = threadIdx.x, lane = tid & 63, w = tid >> 6;
  const int lo = lane & 15, g = lane >> 4;
  const int wm = w >> 2, wn = w & 3;    // 2M x 4N
  const int m0 = blockIdx.y * 128, n0 = blockIdx.x * 256;
  const int NT = K >> 6;
  const int aswz = (lo & 7) << 4;
  const int t8 = tid >> 3, t7 = tid & 7;
  const int swc = (t7 ^ (t8 & 7)) * 8;  // shorts

  const short* As = Ab + (size_t)(m0 + t8) * K + swc;
  const short* Bs[4];
#pragma unroll
  for (int jj = 0; jj < 4; ++jj) {
    int row = (t8 >> 4) * 64 + jj * 16 + (t8 & 15);
    Bs[jj] = Btb + (size_t)(n0 + row) * K + swc;
  }
  auto SA = [&](char* nb, int jj, int y) {
    gload16(As + (size_t)jj * 64 * K + y * 64, nb + tid * 16 + jj * 8192);
  };
  auto SB = [&](char* nb, int jj, int y) {
    gload16(Bs[jj] + y * 64, nb + 16384 + tid * 16 + jj * 8192);
  };

  f32x4 acc[4][4];
#pragma unroll
  for (int i = 0; i < 4; ++i)
#pragma unroll
    for (int j = 0; j < 4; ++j) acc[i][j] = (f32x4){0.f, 0.f, 0.f, 0.f};

  s16x8 a[4][2], bq[2][2];

#define OLDB(P) \
  _Pragma("unroll") for (int jj = 0; jj < 2; ++jj) \
  _Pragma("unroll") for (int kk = 0; kk < 2; ++kk) \
    bq[jj][kk] = *(const s16x8*)(bu + 16384 + (((P) * 2 + jj) * 64 + wn * 16 + lo) * 128 + ((kk * 64 + g * 16) ^ aswz));
#define OMMQ(P) \
  __builtin_amdgcn_s_setprio(1); \
  _Pragma("unroll") for (int i = 0; i < 4; ++i) \
  _Pragma("unroll") for (int jj = 0; jj < 2; ++jj) { \
    f32x4 z = __builtin_amdgcn_mfma_f32_16x16x32_bf16(a[i][0], bq[jj][0], acc[i][(P) * 2 + jj], 0, 0, 0); \
    acc[i][(P) * 2 + jj] = __builtin_amdgcn_mfma_f32_16x16x32_bf16(a[i][1], bq[jj][1], z, 0, 0, 0); \
  } \
  __builtin_amdgcn_s_setprio(0);

  SA(lds, 0, 0); SA(lds, 1, 0);
  SB(lds, 0, 0); SB(lds, 1, 0); SB(lds, 2, 0); SB(lds, 3, 0);
  asm volatile("s_waitcnt vmcnt(0)" ::: "memory");
  __builtin_amdgcn_s_barrier();

  for (int t = 0; t < NT; ++t) {
    const char* bu = lds + (t & 1) * SLOT;
    char* nb = lds + ((t + 1) & 1) * SLOT;
    const bool pre = (t + 1 < NT);
    // ---- ph0: cols 0,1
#pragma unroll
    for (int i = 0; i < 4; ++i)
#pragma unroll
      for (int kk = 0; kk < 2; ++kk)
        a[i][kk] = *(const s16x8*)(bu + (wm * 64 + i * 16 + lo) * 128 + ((kk * 64 + g * 16) ^ aswz));
    OLDB(0);
    if (pre) { SA(nb, 0, t + 1); SA(nb, 1, t + 1); SB(nb, 0, t + 1); SB(nb, 1, t + 1); }
    TOPSYNC();
    OMMQ(0);
    if (pre) asm volatile("s_waitcnt vmcnt(4)" ::: "memory");
    else     asm volatile("s_waitcnt vmcnt(0)" ::: "memory");
    __builtin_amdgcn_s_barrier();
    // ---- ph1: cols 2,3
    OLDB(1);
    if (pre) { SB(nb, 2, t + 1); SB(nb, 3, t + 1); }
    TOPSYNC();
    OMMQ(1);
    if (pre) asm volatile("s_waitcnt vmcnt(2)" ::: "memory");
    __builtin_amdgcn_s_barrier();
  }
#undef OLDB
#undef OMMQ

#pragma unroll
  for (int i = 0; i < 4; ++i)
#pragma unroll
    for (int j = 0; j < 4; ++j)
#pragma unroll
      for (int r = 0; r < 4; ++r) {
        int row = m0 + wm * 64 + i * 16 + g * 4 + r;
        int col = n0 + wn * 64 + j * 16 + lo;
        C0[(size_t)row * 4096 + col] = acc[i][j][r];
      }
}

// ---------------------------------------------------------------------------
// ropeinj_kernel: fused {rope Q | rope K | virtual-KV inject}.
// ---------------------------------------------------------------------------
__global__ __launch_bounds__(256) void ropeinj_kernel(
    const float* __restrict__ q_projf, const float* __restrict__ k_projf,
    const float* __restrict__ qnw, const float* __restrict__ knw,
    const float* __restrict__ cosT, const float* __restrict__ sinT,
    const float* __restrict__ vk, const float* __restrict__ vv,
    const float* __restrict__ logit,
    short* __restrict__ Qr, short* __restrict__ Kr, short* __restrict__ Vt,
    float qscale)
{
  const int bid = blockIdx.x, tid = threadIdx.x;
  if (bid < 20480) {
    const float* proj; const float* nw; short* outp;
    int nh_shift, rows_total, row0, kswz; float qs; int wid;
    if (bid < 16384) {
      proj = q_projf; nw = qnw; outp = Qr; nh_shift = 5;
      rows_total = T_SEQ; row0 = 0; qs = qscale; kswz = 0;
      wid = bid * 4 + (tid >> 6);
    } else {
      proj = k_projf; nw = knw; outp = Kr; nh_shift = 3;
      rows_total = TKV; row0 = RVIRT; qs = 1.0f; kswz = 1;
      wid = (bid - 16384) * 4 + (tid >> 6);
    }
    int lane = tid & 63;
    int nh = 1 << nh_shift;
    int t = wid >> nh_shift;
    int hh = wid & (nh - 1);
    const float* src = proj + (size_t)t * (nh * HD) + hh * HD;
    float x1 = src[lane];
    float x2 = src[lane + 64];
    float ss = x1 * x1 + x2 * x2;
#pragma unroll
    for (int off = 32; off > 0; off >>= 1) ss += __shfl_xor(ss, off, 64);
    float rms = rsqrtf(ss * (1.0f / 128.0f) + 1e-6f);
    float n1 = x1 * rms * nw[lane];
    float n2 = x2 * rms * nw[lane + 64];
    float c1 = cosT[t * HD + lane], c2 = cosT[t * HD + lane + 64];
    float s1 = sinT[t * HD + lane], s2 = sinT[t * HD + lane + 64];
    short* dst = outp + ((size_t)hh * rows_total + row0 + t) * HD;
    int sw = kswz ? (((row0 + t) & 7) << 3) : 0;
    dst[lane ^ sw]        = f2bf((n1 * c1 - n2 * s1) * qs);
    dst[(lane + 64) ^ sw] = f2bf((n2 * c2 + n1 * s2) * qs);
  } else {
    int idx = (bid - 20480) * 256 + tid;   // < 8*128*128
    float alpha = 0.5f / (1.0f + __expf(-logit[0]));
    int kv = idx >> 14, rem = idx & 16383, r = rem >> 7, d = rem & 127;
    int swk = (r & 7) << 3;
    Kr[((size_t)kv * TKV + r) * HD + (d ^ swk)] = f2bf(vk[idx] * alpha);
    int swv = ((d ^ (d >> 3)) & 7) << 3;
    Vt[((size_t)kv * HD + d) * TKV + (r ^ swv)] = f2bf(vv[idx] * alpha);
  }
}

// ---------------------------------------------------------------------------
// attn_wo_kernel: fused {flash attention v6 | transpose Wo}.  (frozen, r10)
// ---------------------------------------------------------------------------
__global__ __launch_bounds__(256, 2) void attn_wo_kernel(const short* __restrict__ Qr,
    const short* __restrict__ Kr, const short* __restrict__ Vt,
    short* __restrict__ out, const float* __restrict__ Wo,
    short* __restrict__ Wot)
{
  __shared__ __align__(16) char smem[81920];
  const int tid = threadIdx.x;
  const int bid = blockIdx.x;

  if (bid >= 512) {
    // ---------------- Wo transpose branch ----------------
    float* tile = (float*)smem;               // [64][65]
    int b = bid - 512;
    const int n0 = (b & 63) * 64, k0 = (b >> 6) * 64;
    const int N = 4096, K = 4096;
    const int rr = tid >> 4, c4 = (tid & 15) * 4;
#pragma unroll
    for (int it = 0; it < 4; ++it) {
      int row = it * 16 + rr;
      float4v v = *(const float4v*)(Wo + (size_t)(k0 + row) * N + n0 + c4);
      tile[row * 65 + c4] = v[0]; tile[row * 65 + c4 + 1] = v[1];
      tile[row * 65 + c4 + 2] = v[2]; tile[row * 65 + c4 + 3] = v[3];
    }
    __syncthreads();
    const int n = tid >> 3, seg = tid & 7;
#pragma unroll
    for (int it = 0; it < 2; ++it) {
      int nn = it * 32 + n;
      s16x8 o;
#pragma unroll
      for (int j = 0; j < 8; ++j) o[j] = f2bf(tile[(seg * 8 + j) * 65 + nn]);
      *(s16x8*)(Wot + (size_t)(n0 + nn) * K + k0 + seg * 8) = o;
    }
    return;
  }

  // ---------------- attention v6 branch ----------------
  short* Ks0 = (short*)smem;                  // [2][64*128]
  short* Vs0 = (short*)(smem + 32768);        // [2][128*64]
  char*  Ps  = smem + 65536;                  // per wave: 2KB A + 2KB B
  const int lane = tid & 63, w = tid >> 6;
  const int kvh = bid & 7;                    // XCD-aligned kv-head
  const int r5 = bid >> 3;
  const int h = kvh * 4 + (r5 & 3);
  const int bx = r5 >> 2;                     // 0..15
  const int lo = lane & 15, g = lane >> 4;
  const int q0A = bx * 64, q0B = (31 - bx) * 64;
  const int ntA = bx + 3, ntB = 34 - bx;
  char* PsA = Ps + w * 4096;
  char* PsB = PsA + 2048;
  const short* Kb = Kr + (size_t)kvh * TKV * HD;
  const short* Vb = Vt + (size_t)kvh * HD * TKV;

  s16x8 qfA[4], qfB[4];
#pragma unroll
  for (int kk = 0; kk < 4; ++kk) {
    qfA[kk] = *(const s16x8*)(Qr + ((size_t)h * T_SEQ + q0A + w * 16 + lo) * HD + kk * 32 + g * 8);
    qfB[kk] = *(const s16x8*)(Qr + ((size_t)h * T_SEQ + q0B + w * 16 + lo) * HD + kk * 32 + g * 8);
  }
  const int qrA = q0A + w * 16 + lo, qrB = q0B + w * 16 + lo;

  float mA = -3.0e38f, lA = 0.f, mB = -3.0e38f, lB = 0.f;
  f32x4 oA[8] = {}, oB[8] = {};

  auto STAGE = [&](int kvt, int buf) {
#pragma unroll
    for (int p = 0; p < 4; ++p) {
      int ci = p * 256 + tid;
      gload16(Kb + (size_t)(kvt * 64 + (ci >> 4)) * HD + (ci & 15) * 8,
              (char*)(Ks0 + buf * 8192) + ci * 16);
      gload16(Vb + (size_t)(ci >> 3) * TKV + kvt * 64 + (ci & 7) * 8,
              (char*)(Vs0 + buf * 8192) + ci * 16);
    }
  };

  STAGE(0, 0);
  asm volatile("s_waitcnt vmcnt(0)" ::: "memory");
  __syncthreads();

  for (int kvt = 0; kvt < ntB; ++kvt) {
    const int cur = kvt & 1;
    if (kvt + 1 < ntB) STAGE(kvt + 1, cur ^ 1);
    const char* Ksb = (const char*)(Ks0 + cur * 8192);
    const char* Vsb = (const char*)(Vs0 + cur * 8192);
    const bool doA = (kvt < ntA);
    const bool maskA = (kvt == ntA - 1);
    const bool maskB = (kvt == ntB - 1);

    // ---- S phase: shared kf -> both subtiles
    f32x4 sA[4], sB[4];
    __builtin_amdgcn_s_setprio(1);
#pragma unroll
    for (int cj = 0; cj < 4; ++cj) {
      f32x4 zA = {}, zB = {};
      const int kr = cj * 16 + lo;
#pragma unroll
      for (int kk = 0; kk < 4; ++kk) {
        s16x8 kf = *(const s16x8*)(Ksb + ((kr * 256 + kk * 64 + g * 16) ^ ((kr & 7) << 4)));
        zB = __builtin_amdgcn_mfma_f32_16x16x32_bf16(kf, qfB[kk], zB, 0, 0, 0);
        if (doA) zA = __builtin_amdgcn_mfma_f32_16x16x32_bf16(kf, qfA[kk], zA, 0, 0, 0);
      }
      sA[cj] = zA; sB[cj] = zB;
    }
    __builtin_amdgcn_s_setprio(0);

    // ---- softmax per subtile (same math as v4-v6)
#define SOFTMAX(S, M, L, O, PSW, MASKED, QR) { \
      float mx = -3.0e38f; \
      _Pragma("unroll") for (int cj = 0; cj < 4; ++cj) \
      _Pragma("unroll") for (int r = 0; r < 4; ++r) { \
        float s = S[cj][r]; \
        if (MASKED) { \
          int k = kvt * 64 + cj * 16 + g * 4 + r; \
          bool ok = (k < RVIRT) || (k - RVIRT <= (QR)); \
          s = ok ? s : -3.0e38f; S[cj][r] = s; \
        } \
        mx = fmaxf(mx, s); \
      } \
      mx = fmaxf(mx, __shfl_xor(mx, 16, 64)); \
      mx = fmaxf(mx, __shfl_xor(mx, 32, 64)); \
      if (__any(mx > M + 8.0f)) { \
        float mnew = fmaxf(M, mx); \
        float fs = __expf(M - mnew); \
        M = mnew; L *= fs; \
        _Pragma("unroll") for (int r = 0; r < 4; ++r) { \
          float fsq = __shfl(fs, g * 4 + r, 64); \
          _Pragma("unroll") for (int dj = 0; dj < 8; ++dj) O[dj][r] *= fsq; \
        } \
      } \
      float rowsum = 0.f; \
      _Pragma("unroll") for (int cj = 0; cj < 4; ++cj) { \
        s16x4 pk; \
        _Pragma("unroll") for (int r = 0; r < 4; ++r) { \
          float pv = __expf(S[cj][r] - M); \
          rowsum += pv; pk[r] = f2bf(pv); \
        } \
        *(s16x4*)(PSW + ((lo * 128 + cj * 32 + g * 8) ^ ((lo & 7) << 4))) = pk; \
      } \
      rowsum += __shfl_xor(rowsum, 16, 64); \
      rowsum += __shfl_xor(rowsum, 32, 64); \
      L += rowsum; \
    }
    if (doA) SOFTMAX(sA, mA, lA, oA, PsA, maskA, qrA);
    SOFTMAX(sB, mB, lB, oB, PsB, maskB, qrB);
#undef SOFTMAX

    // ---- PV phase: shared vf -> both subtiles
    s16x8 pfA[2], pfB[2];
#pragma unroll
    for (int k2 = 0; k2 < 2; ++k2) {
      pfB[k2] = *(const s16x8*)(PsB + ((lo * 128 + k2 * 64 + g * 16) ^ ((lo & 7) << 4)));
      if (doA) pfA[k2] = *(const s16x8*)(PsA + ((lo * 128 + k2 * 64 + g * 16) ^ ((lo & 7) << 4)));
    }
    __builtin_amdgcn_s_setprio(1);
#pragma unroll
    for (int dj = 0; dj < 8; ++dj) {
      const int d = dj * 16 + lo;
      const int vswz = ((d ^ (d >> 3)) & 7) << 4;
#pragma unroll
      for (int k2 = 0; k2 < 2; ++k2) {
        s16x8 vf = *(const s16x8*)(Vsb + ((d * 128 + k2 * 64 + g * 16) ^ vswz));
        oB[dj] = __builtin_amdgcn_mfma_f32_16x16x32_bf16(pfB[k2], vf, oB[dj], 0, 0, 0);
        if (doA) oA[dj] = __builtin_amdgcn_mfma_f32_16x16x32_bf16(pfA[k2], vf, oA[dj], 0, 0, 0);
      }
    }
    __builtin_amdgcn_s_setprio(0);

    asm volatile("s_waitcnt vmcnt(0)" ::: "memory");  // next-tile loads landed
    __syncthreads();
  }

  // epilogue: o row q = g*4 + r; l lives on lane with lo == q (any g)
#pragma unroll
  for (int r = 0; r < 4; ++r) {
    float lqA = __shfl(lA, g * 4 + r, 64);
    float lqB = __shfl(lB, g * 4 + r, 64);
    float iA = 1.f / lqA, iB = 1.f / lqB;
#pragma unroll
    for (int dj = 0; dj < 8; ++dj) {
      int col = h * HD + dj * 16 + lo;
      int rowA = q0A + w * 16 + g * 4 + r;
      int rowB = q0B + w * 16 + g * 4 + r;
      out[(size_t)rowA * (NH * HD) + col] = f2bf(oA[dj][r] * iA);
      out[(size_t)rowB * (NH * HD) + col] = f2bf(oB[dj][r] * iB);
    }
  }
}

// ---------------------------------------------------------------------------
extern "C" void kernel_launch(void* const* d_in, const int* in_sizes, int n_in,
                              void* d_out, int out_size, void* d_ws, size_t ws_size,
                              hipStream_t stream)
{
  const float* hidden = (const float*)d_in[0];
  // d_in[1] = attention_mask: structurally known (causal + R visible), unused.
  const float* cosT = (const float*)d_in[2];
  const float* sinT = (const float*)d_in[3];
  const float* vk   = (const float*)d_in[4];
  const float* vv   = (const float*)d_in[5];
  const float* Wq   = (const float*)d_in[6];
  const float* Wk   = (const float*)d_in[7];
  const float* Wv   = (const float*)d_in[8];
  const float* Wo   = (const float*)d_in[9];
  const float* qnw  = (const float*)d_in[10];
  const float* knw  = (const float*)d_in[11];
  const float* alog = (const float*)d_in[12];

  char* ws = (char*)d_ws;
  float* q_projf = (float*)ws;                         // 33,554,432 B
  float* k_projf = (float*)(ws + 33554432);            //  8,388,608 B
  short* Vt      = (short*)(ws + 41943040);            //  4,456,448 B
  short* Qr      = (short*)(ws + 46399488);            // 16,777,216 B
  short* Kr      = (short*)(ws + 63176704);            //  4,456,448 B
  short* Xb      = (short*)(ws + 67633152);            // 16,777,216 B
  short* Wall    = (short*)(ws + 84410368);            // 50,331,648 B  (Wq|Wk|Wv)^T
  short* Wot     = Wall;                               // reused after QKV gemm
  short* attn_out = (short*)ws;                        // reuses q_projf (bf16)
  float* outp = (float*)d_out;

  const float qscale = 0.08838834764831845f;           // 128^-0.5

  dim3 blk(256);
  prep_kernel<<<dim3(10240), blk, 0, stream>>>(hidden, Xb, Wq, Wk, Wv, Wall);
  gemm_qkv<<<dim3(32, 8), dim3(512), 0, stream>>>(Xb, Wall, q_projf, k_projf, Vt, DMODEL);
  ropeinj_kernel<<<dim3(20992), blk, 0, stream>>>(q_projf, k_projf, qnw, knw,
      cosT, sinT, vk, vv, alog, Qr, Kr, Vt, qscale);
  attn_wo_kernel<<<dim3(4608), blk, 0, stream>>>(Qr, Kr, Vt, attn_out, Wo, Wot);
  gemm_out<<<dim3(16, 16), dim3(512), 0, stream>>>(attn_out, Wot, outp, 4096);
}